// Round 6
// baseline (349.891 us; speedup 1.0000x reference)
//
#include <hip/hip_runtime.h>
#include <hip/hip_bf16.h>

typedef __attribute__((ext_vector_type(8))) unsigned short u16x8;
typedef __attribute__((ext_vector_type(8))) __bf16 bf16x8;
typedef __attribute__((ext_vector_type(4))) float f32x4;

// pack two f32 -> two bf16 (round-half-up): 2 adds + 1 v_perm_b32
__device__ __forceinline__ unsigned pack_bf2(float lo, float hi) {
  unsigned a = __float_as_uint(lo) + 0x8000u;
  unsigned b = __float_as_uint(hi) + 0x8000u;
  return __builtin_amdgcn_perm(b, a, 0x07060302);
}

__device__ __forceinline__ unsigned short f2bf(float f) {
  unsigned u = __float_as_uint(f);
  return (unsigned short)((u + 0x7fffu + ((u >> 16) & 1u)) >> 16);  // RNE (prep only)
}

// swizzled byte offset into a [rows][stride bytes] bf16 buffer (16B-chunk XOR by row&7)
__device__ __forceinline__ int aswz(int row, int feat, int stride) {
  return row * stride + (((feat >> 3) ^ (row & 7)) << 4) + (feat & 7) * 2;
}

// ---- fused: weight transpose/pack + degree histogram ----
__global__ void prep_hist(const float* __restrict__ W1, const float* __restrict__ W2,
                          const float* __restrict__ W3, const float* __restrict__ W4,
                          unsigned short* __restrict__ wt,
                          const int* __restrict__ ei, int* __restrict__ histI, int E) {
  int i = blockIdx.x * 256 + threadIdx.x;
  if (i < 22528) {
    float v; int n, k, K, base;
    if (i < 4096)       { n = i >> 6, k = i & 63;  K = 64;  base = 0;     v = W1[k * 64 + n]; }
    else if (i < 12288) { int j = i - 4096;  n = j >> 6, k = j & 63;  K = 64;  base = 4096;  v = W2[k * 128 + n]; }
    else if (i < 20480) { int j = i - 12288; n = j >> 7, k = j & 127; K = 128; base = 12288; v = W3[k * 64 + n]; }
    else                { int j = i - 20480; n = j >> 6, k = j & 63;  K = 64;  base = 20480; v = W4[k * 32 + n]; }
    int o = base + n * K + ((((k >> 3) ^ (n & 7)) << 3) + (k & 7));
    wt[o] = f2bf(v);
  }
  if (i < E) atomicAdd(&histI[ei[E + i]], 1);
}

// phase 1: per-block exclusive scan of 2048 elems (256 thr x 8), write block sums
__global__ void scan_blocks(const int* __restrict__ histI, int* __restrict__ row_start,
                            int* __restrict__ blockSums, int N) {
  __shared__ int wsum[4];
  const int lane = threadIdx.x & 63, w = threadIdx.x >> 6;
  const int i0 = blockIdx.x * 2048 + threadIdx.x * 8;
  int v[8];
#pragma unroll
  for (int j = 0; j < 8; ++j) { int i = i0 + j; v[j] = (i < N) ? histI[i] : 0; }
  int s = 0;
#pragma unroll
  for (int j = 0; j < 8; ++j) { int t = v[j]; v[j] = s; s += t; }
  int ss = s;
#pragma unroll
  for (int d = 1; d < 64; d <<= 1) { int t = __shfl_up(ss, d, 64); if (lane >= d) ss += t; }
  if (lane == 63) wsum[w] = ss;
  __syncthreads();
  int wOff = 0;
#pragma unroll
  for (int k = 0; k < 4; ++k) if (k < w) wOff += wsum[k];
  const int tOff = wOff + (ss - s);
#pragma unroll
  for (int j = 0; j < 8; ++j) { int i = i0 + j; if (i < N) row_start[i] = tOff + v[j]; }
  if (threadIdx.x == 255) blockSums[blockIdx.x] = wOff + ss;
}

// phase 2: single wave -> exclusive block offsets (nb <= 64)
__global__ void scan_tops(int* __restrict__ blockSums, int nb) {
  const int lane = threadIdx.x;
  int v = (lane < nb) ? blockSums[lane] : 0;
  int s = v;
#pragma unroll
  for (int d = 1; d < 64; d <<= 1) { int t = __shfl_up(s, d, 64); if (lane >= d) s += t; }
  if (lane < nb) blockSums[lane] = s - v;
}

// fill CSR edge list (block offset folded in) + zero the output buffer
__global__ void fill_kernel(const int* __restrict__ ei, const int* __restrict__ row_start,
                            const int* __restrict__ blockSums, int* __restrict__ wcnt,
                            int2* __restrict__ edlist, float* __restrict__ out,
                            int E, int Ntot) {
  int e = blockIdx.x * 256 + threadIdx.x;
  if (e < Ntot) out[e] = 0.0f;
  if (e >= E) return;
  int d = ei[E + e];
  int slot = atomicAdd(&wcnt[d], 1);
  edlist[row_start[d] + blockSums[d >> 11] + slot] = make_int2(e, d);
}

// ---- one MLP layer over a 32-edge tile (2 sub-tiles share each weight fragment) ----
template <int MT, int KS, int SS, int DS>
__device__ __forceinline__ void mlp_layer2(const unsigned char* src, unsigned char* dst,
                                           const unsigned char* wl, const float* biasL, int lane) {
  const int edge = lane & 15, g = lane >> 4;
  asm volatile("s_waitcnt lgkmcnt(0)" ::: "memory");
  u16x8 bfrag[2][KS];
#pragma unroll
  for (int s = 0; s < 2; ++s)
#pragma unroll
    for (int ks = 0; ks < KS; ++ks)
      bfrag[s][ks] = *(const u16x8*)(src + aswz(s * 16 + edge, ks * 32 + g * 8, SS));
#pragma unroll
  for (int mt = 0; mt < MT; ++mt) {
    const int n = mt * 16 + edge;
    u16x8 af[KS];
#pragma unroll
    for (int ks = 0; ks < KS; ++ks)
      af[ks] = *(const u16x8*)(wl + n * (KS * 64) + (((ks * 4 + g) ^ (edge & 7)) << 4));
    const float4 bv = *(const float4*)(biasL + mt * 16 + g * 4);
#pragma unroll
    for (int s = 0; s < 2; ++s) {
      f32x4 acc = {bv.x, bv.y, bv.z, bv.w};
      __builtin_amdgcn_s_setprio(1);
#pragma unroll
      for (int ks = 0; ks < KS; ++ks)
        acc = __builtin_amdgcn_mfma_f32_16x16x32_bf16(
            __builtin_bit_cast(bf16x8, af[ks]), __builtin_bit_cast(bf16x8, bfrag[s][ks]),
            acc, 0, 0, 0);
      __builtin_amdgcn_s_setprio(0);
      const int fb = mt * 16 + g * 4;
      uint2 q;
      q.x = pack_bf2(fmaxf(acc[0], 0.f), fmaxf(acc[1], 0.f));
      q.y = pack_bf2(fmaxf(acc[2], 0.f), fmaxf(acc[3], 0.f));
      *(uint2*)(dst + aswz(s * 16 + edge, fb, DS)) = q;
    }
  }
}

// gather prefetch for a 32-edge tile: each lane stages half of one edge (16 feats x+ea)
__device__ __forceinline__ void load_tile32(int ebase, int E, const int2* __restrict__ edlist,
                                            const float* __restrict__ x, const float* __restrict__ ea,
                                            int lane, float4 (&px)[4], float4 (&pe)[4],
                                            int& d0, int& d1) {
  const int el = ebase + (lane >> 1);
  const int part = lane & 1;
#pragma unroll
  for (int j = 0; j < 4; ++j) { px[j] = make_float4(0.f, 0.f, 0.f, 0.f); pe[j] = px[j]; }
  if (el < E) {
    const int2 ed = edlist[el];
    const float4* xp = (const float4*)(x + (size_t)ed.y * 32 + part * 16);
    const float4* ep = (const float4*)(ea + (size_t)ed.x * 32 + part * 16);
#pragma unroll
    for (int j = 0; j < 4; ++j) { px[j] = xp[j]; pe[j] = ep[j]; }
  }
  const int p0 = ebase + (lane & 15), p1 = p0 + 16;
  d0 = (p0 < E) ? edlist[p0].y : -1;
  d1 = (p1 < E) ? edlist[p1].y : -1;
}

// LDS layout: [weights 45056][bias 1152][8 waves x (X 8192 + Y 4096)]
#define BIAS_OFF 45056
#define ACT_OFF  46208

__global__ __launch_bounds__(512, 2)
void gnn_main(const float* __restrict__ x, const int2* __restrict__ edlist,
              const float* __restrict__ ea, const unsigned short* __restrict__ wt,
              const float* __restrict__ b1, const float* __restrict__ b2,
              const float* __restrict__ b3, const float* __restrict__ b4,
              float* __restrict__ out, int E, int numTiles) {
  __shared__ __align__(16) unsigned char lds[ACT_OFF + 8 * 12288];
  {
    const u16x8* gw = (const u16x8*)wt;
    u16x8* lw = (u16x8*)lds;
    for (int i = threadIdx.x; i < 2816; i += 512) lw[i] = gw[i];
    float* biasW = (float*)(lds + BIAS_OFF);
    for (int i = threadIdx.x; i < 288; i += 512) {
      float v;
      if (i < 64) v = b1[i];
      else if (i < 192) v = b2[i - 64];
      else if (i < 256) v = b3[i - 192];
      else v = b4[i - 256];
      biasW[i] = v;
    }
  }
  __syncthreads();

  const int lane = threadIdx.x & 63, wid = threadIdx.x >> 6;
  const int edge = lane & 15, g = lane >> 4;
  const float* biasLds = (const float*)(lds + BIAS_OFF);
  unsigned char* X = lds + ACT_OFF + wid * 12288;   // 32 rows x 256B (up to 128 feats)
  unsigned char* Y = X + 8192;                      // 32 rows x 128B (up to 64 feats)
  const unsigned char* wl1 = lds;
  const unsigned char* wl2 = lds + 8192;
  const unsigned char* wl3 = lds + 24576;
  const unsigned char* wl4 = lds + 40960;

  const int wgl = blockIdx.x * 8 + wid;
  const int wstride = gridDim.x * 8;

  float4 px[4], pe[4]; int d0 = -1, d1 = -1;
  if (wgl < numTiles) load_tile32(wgl * 32, E, edlist, x, ea, lane, px, pe, d0, d1);

  for (int tile = wgl; tile < numTiles; tile += wstride) {
    // ---- stage H0 = concat(x[dst], edge_attr) as bf16 [32 edges][64 feats] into X ----
    const int row = lane >> 1, part = lane & 1;
    {
      uint4 qa, qb;
      qa.x = pack_bf2(px[0].x, px[0].y); qa.y = pack_bf2(px[0].z, px[0].w);
      qa.z = pack_bf2(px[1].x, px[1].y); qa.w = pack_bf2(px[1].z, px[1].w);
      qb.x = pack_bf2(px[2].x, px[2].y); qb.y = pack_bf2(px[2].z, px[2].w);
      qb.z = pack_bf2(px[3].x, px[3].y); qb.w = pack_bf2(px[3].z, px[3].w);
      *(uint4*)(X + aswz(row, part * 16, 256)) = qa;
      *(uint4*)(X + aswz(row, part * 16 + 8, 256)) = qb;
      qa.x = pack_bf2(pe[0].x, pe[0].y); qa.y = pack_bf2(pe[0].z, pe[0].w);
      qa.z = pack_bf2(pe[1].x, pe[1].y); qa.w = pack_bf2(pe[1].z, pe[1].w);
      qb.x = pack_bf2(pe[2].x, pe[2].y); qb.y = pack_bf2(pe[2].z, pe[2].w);
      qb.z = pack_bf2(pe[3].x, pe[3].y); qb.w = pack_bf2(pe[3].z, pe[3].w);
      *(uint4*)(X + aswz(row, 32 + part * 16, 256)) = qa;
      *(uint4*)(X + aswz(row, 32 + part * 16 + 8, 256)) = qb;
    }
    const int cd0 = d0, cd1 = d1;

    // ---- issue next tile's gather; drains under the MFMA chain ----
    const int nt = tile + wstride;
    float4 npx[4], npe[4]; int nd0 = -1, nd1 = -1;
    if (nt < numTiles) load_tile32(nt * 32, E, edlist, x, ea, lane, npx, npe, nd0, nd1);
    else {
#pragma unroll
      for (int j = 0; j < 4; ++j) { npx[j] = make_float4(0.f,0.f,0.f,0.f); npe[j] = npx[j]; }
    }

    mlp_layer2<4, 2, 256, 128>(X, Y, wl1, biasLds + 0,   lane);   // 64 -> 64
    mlp_layer2<8, 2, 128, 256>(Y, X, wl2, biasLds + 64,  lane);   // 64 -> 128
    mlp_layer2<4, 4, 256, 128>(X, Y, wl3, biasLds + 192, lane);   // 128 -> 64

    // ---- layer 4 (both sub-tiles) + segmented lane-reduce + sparse atomics ----
    asm volatile("s_waitcnt lgkmcnt(0)" ::: "memory");
    u16x8 bf4[2][2];
#pragma unroll
    for (int s = 0; s < 2; ++s)
#pragma unroll
      for (int ks = 0; ks < 2; ++ks)
        bf4[s][ks] = *(const u16x8*)(Y + aswz(s * 16 + edge, ks * 32 + g * 8, 128));
    u16x8 af4[2][2];
#pragma unroll
    for (int mt = 0; mt < 2; ++mt)
#pragma unroll
      for (int ks = 0; ks < 2; ++ks)
        af4[mt][ks] = *(const u16x8*)(wl4 + (mt * 16 + edge) * 128 + (((ks * 4 + g) ^ (edge & 7)) << 4));

#pragma unroll
    for (int s = 0; s < 2; ++s) {
      float vals[8];
#pragma unroll
      for (int mt = 0; mt < 2; ++mt) {
        const float4 bv = *(const float4*)(biasLds + 256 + mt * 16 + g * 4);
        f32x4 acc = {bv.x, bv.y, bv.z, bv.w};
        __builtin_amdgcn_s_setprio(1);
#pragma unroll
        for (int ks = 0; ks < 2; ++ks)
          acc = __builtin_amdgcn_mfma_f32_16x16x32_bf16(
              __builtin_bit_cast(bf16x8, af4[mt][ks]), __builtin_bit_cast(bf16x8, bf4[s][ks]),
              acc, 0, 0, 0);
        __builtin_amdgcn_s_setprio(0);
#pragma unroll
        for (int r = 0; r < 4; ++r) vals[mt * 4 + r] = fmaxf(acc[r], 0.f);
      }
      const int curDst = s ? cd1 : cd0;
      const int li = edge;
      const int prev = __shfl_up(curDst, 1, 16);
      const bool is_head = (li == 0) || (prev != curDst);
      const unsigned long long hb = __ballot(is_head);
      const unsigned gm = (unsigned)((hb >> (g * 16)) & 0xFFFFu);
      const unsigned below = gm & ((1u << li) | ((1u << li) - 1u));
      const int dist = li - (31 - __clz(below));
#pragma unroll
      for (int d = 1; d < 16; d <<= 1) {
#pragma unroll
        for (int t = 0; t < 8; ++t) {
          const float tv = __shfl_up(vals[t], d, 16);
          if (dist >= d) vals[t] += tv;
        }
      }
      const bool is_end = (li == 15) || ((gm >> (li + 1)) & 1u);
      if (is_end && curDst >= 0) {
        float* op = out + (size_t)curDst * 32 + g * 4;
#pragma unroll
        for (int t = 0; t < 4; ++t) unsafeAtomicAdd(op + t, vals[t]);
#pragma unroll
        for (int t = 0; t < 4; ++t) unsafeAtomicAdd(op + 16 + t, vals[4 + t]);
      }
    }

#pragma unroll
    for (int j = 0; j < 4; ++j) { px[j] = npx[j]; pe[j] = npe[j]; }
    d0 = nd0; d1 = nd1;
  }
}

__global__ void div_kernel(float* __restrict__ out, const int* __restrict__ histI, int total) {
  int i = blockIdx.x * 256 + threadIdx.x;
  if (i < total) out[i] = out[i] / fmaxf((float)histI[i >> 5], 1.0f);
}

extern "C" void kernel_launch(void* const* d_in, const int* in_sizes, int n_in,
                              void* d_out, int out_size, void* d_ws, size_t ws_size,
                              hipStream_t stream) {
  const float* x  = (const float*)d_in[0];
  const int*   ei = (const int*)d_in[1];
  const float* ea = (const float*)d_in[2];
  const float* W1 = (const float*)d_in[3];
  const float* b1 = (const float*)d_in[4];
  const float* W2 = (const float*)d_in[5];
  const float* b2 = (const float*)d_in[6];
  const float* W3 = (const float*)d_in[7];
  const float* b3 = (const float*)d_in[8];
  const float* W4 = (const float*)d_in[9];
  const float* b4 = (const float*)d_in[10];
  const int N = in_sizes[0] / 32;
  const int E = in_sizes[1] / 2;
  float* out = (float*)d_out;

  char* ws = (char*)d_ws;
  size_t off = 0;
  auto alloc = [&](size_t bytes) { size_t o = off; off += (bytes + 255) & ~(size_t)255; return o; };
  size_t hist_off = alloc((size_t)N * 4);
  size_t wcnt_off = alloc((size_t)N * 4);
  int* histI      = (int*)(ws + hist_off);
  int* wcnt       = (int*)(ws + wcnt_off);
  int* row_start  = (int*)(ws + alloc((size_t)(N + 1) * 4));
  int* blockSums  = (int*)(ws + alloc(64 * 4));
  int2* edlist    = (int2*)(ws + alloc((size_t)E * 8));
  unsigned short* wt = (unsigned short*)(ws + alloc(22528 * 2));

  // one memset covers histI + wcnt (adjacent allocations)
  hipMemsetAsync(ws + hist_off, 0, (wcnt_off - hist_off) + (size_t)N * 4, stream);

  const int gridPH = (max(E, 22528) + 255) / 256;
  prep_hist<<<gridPH, 256, 0, stream>>>(W1, W2, W3, W4, wt, ei, histI, E);
  const int nb = (N + 2047) / 2048;
  scan_blocks<<<nb, 256, 0, stream>>>(histI, row_start, blockSums, N);
  scan_tops<<<1, 64, 0, stream>>>(blockSums, nb);
  const int Ntot = N * 32;
  const int gridF = (max(E, Ntot) + 255) / 256;
  fill_kernel<<<gridF, 256, 0, stream>>>(ei, row_start, blockSums, wcnt, edlist, out, E, Ntot);

  const int numTiles = (E + 31) / 32;
  gnn_main<<<256, 512, 0, stream>>>(x, edlist, ea, wt, b1, b2, b3, b4, out, E, numTiles);
  div_kernel<<<(Ntot + 255) / 256, 256, 0, stream>>>(out, histI, Ntot);
}